// Round 1
// baseline (342.529 us; speedup 1.0000x reference)
//
#include <hip/hip_runtime.h>

typedef float  f4  __attribute__((ext_vector_type(4)));
typedef __bf16 bf8 __attribute__((ext_vector_type(8)));

constexpr int B_ = 2, N_ = 1024, M_ = 256, D_ = 576, H1_ = 512, H2_ = 256;

__device__ __forceinline__ void gload_lds16(const void* g, void* l) {
    __builtin_amdgcn_global_load_lds((const __attribute__((address_space(1))) void*)g,
                                     (__attribute__((address_space(3))) void*)l, 16, 0, 0);
}

// ---------------- prep: bf16 conversions + weight transposes ----------------
__global__ __launch_bounds__(256) void k_prep(
    const float* __restrict__ PhiA, const float* __restrict__ PhiB,
    const float* __restrict__ W1a, const float* __restrict__ W1b, const float* __restrict__ W2,
    __bf16* __restrict__ phiAb, __bf16* __restrict__ phiBb,
    __bf16* __restrict__ w1aT, __bf16* __restrict__ w1bT, __bf16* __restrict__ w2T) {
    int i = blockIdx.x * 256 + threadIdx.x;
    constexpr int nA = B_ * N_ * D_;   // 1179648
    constexpr int nB = B_ * M_ * D_;   // 294912
    constexpr int nW1 = D_ * H1_;      // 294912
    constexpr int nW2 = H1_ * H2_;     // 131072
    if (i < nA) { phiAb[i] = (__bf16)PhiA[i]; return; }
    i -= nA;
    if (i < nB) { phiBb[i] = (__bf16)PhiB[i]; return; }
    i -= nB;
    if (i < nW1) { int h = i / D_, k = i - h * D_; w1aT[i] = (__bf16)W1a[k * H1_ + h]; return; }
    i -= nW1;
    if (i < nW1) { int h = i / D_, k = i - h * D_; w1bT[i] = (__bf16)W1b[k * H1_ + h]; return; }
    i -= nW1;
    if (i < nW2) { int n = i >> 9, k = i & 511; w2T[i] = (__bf16)W2[k * H2_ + n]; }
}

// ---------------- proj: [rows x 576] @ [576 x 512] -> f32 (+bias folded) ----
__global__ __launch_bounds__(256, 2) void k_proj(
    const __bf16* __restrict__ phiAb, const __bf16* __restrict__ phiBb,
    const __bf16* __restrict__ w1aT, const __bf16* __restrict__ w1bT,
    const float* __restrict__ b1, float* __restrict__ aproj, float* __restrict__ bproj) {
    __shared__ __bf16 ats[64 * 64];
    __shared__ __bf16 wts[64 * 64];
    const int t = threadIdx.x, l = t & 63, wid = t >> 6;
    const int lane15 = l & 15, hi = l >> 4;
    const int bx = blockIdx.x;
    const __bf16* src; const __bf16* wt; float* out; const float* bias; int rows0;
    if (bx < 32) { src = phiAb; wt = w1aT; out = aproj; bias = b1;      rows0 = bx * 64; }
    else         { src = phiBb; wt = w1bT; out = bproj; bias = nullptr; rows0 = (bx - 32) * 64; }
    const int c0 = blockIdx.y * 64;

    f4 acc[4];
    #pragma unroll
    for (int fr = 0; fr < 4; ++fr) acc[fr] = (f4)0.0f;

    for (int kt = 0; kt < 9; ++kt) {             // K = 576 = 9 * 64
        const int kk0 = kt * 64;
        #pragma unroll
        for (int i = 0; i < 2; ++i) {
            int c = t + i * 256; int row = c >> 3, k8 = c & 7;
            gload_lds16(src + (size_t)(rows0 + row) * D_ + kk0 + ((k8 ^ (row & 7)) * 8),
                        (char*)ats + c * 16);
            gload_lds16(wt + (size_t)(c0 + row) * D_ + kk0 + ((k8 ^ (row & 7)) * 8),
                        (char*)wts + c * 16);
        }
        __syncthreads();
        #pragma unroll
        for (int ks = 0; ks < 2; ++ks) {
            const int ob = ks * 64 + hi * 16;
            int lcol = wid * 16 + lane15;
            int o = lcol * 128 + ob; o ^= (lcol & 7) << 4;
            bf8 bv = *(const bf8*)((const char*)wts + o);
            #pragma unroll
            for (int fr = 0; fr < 4; ++fr) {
                int row = fr * 16 + lane15;
                int oa = row * 128 + ob; oa ^= (row & 7) << 4;
                bf8 av = *(const bf8*)((const char*)ats + oa);
                acc[fr] = __builtin_amdgcn_mfma_f32_16x16x32_bf16(av, bv, acc[fr], 0, 0, 0);
            }
        }
        __syncthreads();
    }
    const int col = c0 + wid * 16 + lane15;
    const float bb = bias ? bias[col] : 0.0f;
    #pragma unroll
    for (int fr = 0; fr < 4; ++fr)
        #pragma unroll
        for (int j = 0; j < 4; ++j)
            out[(size_t)(rows0 + fr * 16 + hi * 4 + j) * H1_ + col] = acc[fr][j] + bb;
}

// ---------------- main fused kernel: relu(aproj+bproj) @ W2 -> relu(+b2) @ W3
__global__ __launch_bounds__(256, 2) void k_main(
    const float* __restrict__ aprojb1, const float* __restrict__ bprojf,
    const __bf16* __restrict__ w2T, const float* __restrict__ b2,
    const float* __restrict__ w3, const float* __restrict__ b3,
    float* __restrict__ outp) {
    __shared__ __bf16 h1s[128 * 64];   // 16 KB
    __shared__ __bf16 w2s[256 * 64];   // 32 KB
    __shared__ float  part[2][128];    // 1 KB

    const int t = threadIdx.x, l = t & 63, wid = t >> 6;
    const int lane15 = l & 15, hi = l >> 4;
    const int wr = wid >> 1, wc = wid & 1;
    const int bid = blockIdx.x;
    const int an = bid >> 1;                 // row into aproj = b*N + n
    const int bb_ = bid >> 11;               // batch
    const int m0 = (bid & 1) * 128;
    const int bprow0 = bb_ * M_ + m0;        // row into bproj
    const int p_base = bid * 128;

    const int r = t >> 1, koff = (t & 1) * 32;
    const float* ap_base = aprojb1 + (size_t)an * H1_ + koff;
    const float* bp_base = bprojf + (size_t)(bprow0 + r) * H1_ + koff;

    f4 acc[4][8];
    #pragma unroll
    for (int fr = 0; fr < 4; ++fr)
        #pragma unroll
        for (int cf = 0; cf < 8; ++cf) acc[fr][cf] = (f4)0.0f;

    for (int kt = 0; kt < 8; ++kt) {         // K = 512 = 8 * 64
        const int kk0 = kt * 64;
        // stage W2^T K-slice [256 cols][64 k] via global_load_lds, source pre-swizzled
        #pragma unroll
        for (int i = 0; i < 8; ++i) {
            int c = t + i * 256; int col = c >> 3, k8 = c & 7;
            gload_lds16(w2T + (size_t)col * H1_ + kk0 + ((k8 ^ (col & 7)) * 8),
                        (char*)w2s + c * 16);
        }
        // construct h1 tile [128 rows][64 k] in regs -> swizzled ds_write_b128
        #pragma unroll
        for (int cc = 0; cc < 4; ++cc) {
            f4 a0  = *(const f4*)(ap_base + kk0 + cc * 8);
            f4 a1  = *(const f4*)(ap_base + kk0 + cc * 8 + 4);
            f4 b0  = *(const f4*)(bp_base + kk0 + cc * 8);
            f4 b1v = *(const f4*)(bp_base + kk0 + cc * 8 + 4);
            bf8 h;
            #pragma unroll
            for (int j = 0; j < 4; ++j) h[j] = (__bf16)fmaxf(a0[j] + b0[j], 0.0f);
            #pragma unroll
            for (int j = 0; j < 4; ++j) h[4 + j] = (__bf16)fmaxf(a1[j] + b1v[j], 0.0f);
            int kq = (t & 1) * 4 + cc;
            int o = r * 128 + kq * 16; o ^= (r & 7) << 4;
            *(bf8*)((char*)h1s + o) = h;
        }
        __syncthreads();
        #pragma unroll
        for (int ks = 0; ks < 2; ++ks) {
            const int ob = ks * 64 + hi * 16;
            bf8 av[4], bv[8];
            #pragma unroll
            for (int fr = 0; fr < 4; ++fr) {
                int row = wr * 64 + fr * 16 + lane15;
                int o = row * 128 + ob; o ^= (row & 7) << 4;
                av[fr] = *(const bf8*)((const char*)h1s + o);
            }
            #pragma unroll
            for (int cf = 0; cf < 8; ++cf) {
                int col = wc * 128 + cf * 16 + lane15;
                int o = col * 128 + ob; o ^= (col & 7) << 4;
                bv[cf] = *(const bf8*)((const char*)w2s + o);
            }
            #pragma unroll
            for (int fr = 0; fr < 4; ++fr)
                #pragma unroll
                for (int cf = 0; cf < 8; ++cf)
                    acc[fr][cf] = __builtin_amdgcn_mfma_f32_16x16x32_bf16(av[fr], bv[cf], acc[fr][cf], 0, 0, 0);
        }
        __syncthreads();
    }

    // epilogue: h2 = relu(acc + b2); out_row = h2 @ W3 + b3
    float b2v[8], w3v[8];
    #pragma unroll
    for (int cf = 0; cf < 8; ++cf) {
        int col = wc * 128 + cf * 16 + lane15;
        b2v[cf] = b2[col]; w3v[cf] = w3[col];
    }
    #pragma unroll
    for (int fr = 0; fr < 4; ++fr) {
        #pragma unroll
        for (int j = 0; j < 4; ++j) {
            float s = 0.0f;
            #pragma unroll
            for (int cf = 0; cf < 8; ++cf)
                s += fmaxf(acc[fr][cf][j] + b2v[cf], 0.0f) * w3v[cf];
            s += __shfl_xor(s, 1); s += __shfl_xor(s, 2);
            s += __shfl_xor(s, 4); s += __shfl_xor(s, 8);
            if (lane15 == 0) part[wc][wr * 64 + fr * 16 + hi * 4 + j] = s;
        }
    }
    __syncthreads();
    if (t < 128) outp[p_base + t] = part[0][t] + part[1][t] + b3[0];
}

extern "C" void kernel_launch(void* const* d_in, const int* in_sizes, int n_in,
                              void* d_out, int out_size, void* d_ws, size_t ws_size,
                              hipStream_t stream) {
    (void)in_sizes; (void)n_in; (void)out_size; (void)ws_size;
    const float* PhiA = (const float*)d_in[0];
    const float* PhiB = (const float*)d_in[1];
    const float* W1a  = (const float*)d_in[2];
    const float* W1b  = (const float*)d_in[3];
    const float* b1   = (const float*)d_in[4];
    const float* W2   = (const float*)d_in[5];
    const float* b2   = (const float*)d_in[6];
    const float* W3   = (const float*)d_in[7];
    const float* b3   = (const float*)d_in[8];
    float* out = (float*)d_out;

    char* ws = (char*)d_ws;
    float*  aproj = (float*)(ws);                 // 4,194,304 B  (b1 folded in)
    float*  bproj = (float*)(ws + 4194304);       // 1,048,576 B
    __bf16* phiAb = (__bf16*)(ws + 5242880);      // 2,359,296 B
    __bf16* phiBb = (__bf16*)(ws + 7602176);      //   589,824 B
    __bf16* w1aT  = (__bf16*)(ws + 8192000);      //   589,824 B
    __bf16* w1bT  = (__bf16*)(ws + 8781824);      //   589,824 B
    __bf16* w2T   = (__bf16*)(ws + 9371648);      //   262,144 B  (total ~9.6 MB)

    k_prep<<<8576, 256, 0, stream>>>(PhiA, PhiB, W1a, W1b, W2, phiAb, phiBb, w1aT, w1bT, w2T);
    k_proj<<<dim3(40, 8), 256, 0, stream>>>(phiAb, phiBb, w1aT, w1bT, b1, aproj, bproj);
    k_main<<<4096, 256, 0, stream>>>(aproj, bproj, w2T, b2, W3, b3, out);
}

// Round 3
// 311.573 us; speedup vs baseline: 1.0994x; 1.0994x over previous
//
#include <hip/hip_runtime.h>

typedef float  f4  __attribute__((ext_vector_type(4)));
typedef __bf16 bf8 __attribute__((ext_vector_type(8)));

constexpr int B_ = 2, N_ = 1024, M_ = 256, D_ = 576, H1_ = 512, H2_ = 256;

__device__ __forceinline__ void gload_lds16(const void* g, void* l) {
    __builtin_amdgcn_global_load_lds((const __attribute__((address_space(1))) void*)g,
                                     (__attribute__((address_space(3))) void*)l, 16, 0, 0);
}
// paired-row layout: logical row r (64B of payload) packed 2-per-128B LDS row,
// XOR-swizzled in 16B slots -> ~2-way max bank aliasing on b128 reads
__device__ __forceinline__ int swz(int row, int inner) {
    return (row >> 1) * 128 + ((((row & 1) << 6) + inner) ^ (((row >> 1) & 7) << 4));
}
// simple 128B-row layout for 64x64 tiles (k_proj)
__device__ __forceinline__ int swz64(int row, int inner) {
    return row * 128 + (inner ^ ((row & 7) << 4));
}

// ---------------- k_tr: coalesced f32->bf16 weight transposes ----------------
__global__ __launch_bounds__(256) void k_tr(
    const float* __restrict__ W1a, const float* __restrict__ W1b, const float* __restrict__ W2,
    __bf16* __restrict__ w1aT, __bf16* __restrict__ w1bT, __bf16* __restrict__ w2T) {
    __shared__ float tl[32][33];
    int bid = blockIdx.x;
    const float* src; __bf16* dst; int R, C, t0;
    if (bid < 288)      { src = W1a; dst = w1aT; R = D_;  C = H1_; t0 = bid; }
    else if (bid < 576) { src = W1b; dst = w1bT; R = D_;  C = H1_; t0 = bid - 288; }
    else                { src = W2;  dst = w2T;  R = H1_; C = H2_; t0 = bid - 576; }
    const int tilesC = C / 32;
    const int r0 = (t0 / tilesC) * 32, c0 = (t0 % tilesC) * 32;
    const int tx = threadIdx.x & 31, ty = threadIdx.x >> 5;
    #pragma unroll
    for (int i = 0; i < 4; ++i)
        tl[ty + i * 8][tx] = src[(size_t)(r0 + ty + i * 8) * C + c0 + tx];
    __syncthreads();
    #pragma unroll
    for (int i = 0; i < 4; ++i)
        dst[(size_t)(c0 + ty + i * 8) * R + r0 + tx] = (__bf16)tl[tx][ty + i * 8];
}

// ------- k_proj: Phi(f32) @ W1T -> aproj(f32,+b1) / bproj(bf16) -------------
__global__ __launch_bounds__(256, 2) void k_proj(
    const float* __restrict__ PhiA, const float* __restrict__ PhiB,
    const __bf16* __restrict__ w1aT, const __bf16* __restrict__ w1bT,
    const float* __restrict__ b1, float* __restrict__ aproj, __bf16* __restrict__ bprojh) {
    __shared__ __bf16 ats[64 * 64];
    __shared__ __bf16 wts[64 * 64];
    const int t = threadIdx.x, l15 = t & 15, hi = (t >> 4) & 3, wid = t >> 6;
    const int bx = blockIdx.x, c0 = blockIdx.y * 64;
    const float* srcf; const __bf16* wt; int rows0; bool isA;
    if (bx < 32) { srcf = PhiA; wt = w1aT; rows0 = bx * 64;        isA = true; }
    else         { srcf = PhiB; wt = w1bT; rows0 = (bx - 32) * 64; isA = false; }
    const int row = t >> 2, khb = (t & 3) * 32;   // 32 bytes = 16 elems per thread-chunk

    f4 acc[4];
    #pragma unroll
    for (int fr = 0; fr < 4; ++fr) acc[fr] = (f4)0.0f;

    for (int kt = 0; kt < 9; ++kt) {              // K = 576 = 9*64
        const int kk0 = kt * 64;
        const float* ap = srcf + (size_t)(rows0 + row) * D_ + kk0 + (khb >> 1);
        f4 a0 = *(const f4*)ap, a1 = *(const f4*)(ap + 4),
           a2 = *(const f4*)(ap + 8), a3 = *(const f4*)(ap + 12);
        bf8 h0, h1v;
        #pragma unroll
        for (int j = 0; j < 4; ++j) {
            h0[j] = (__bf16)a0[j]; h0[4 + j] = (__bf16)a1[j];
            h1v[j] = (__bf16)a2[j]; h1v[4 + j] = (__bf16)a3[j];
        }
        *(bf8*)((char*)ats + swz64(row, khb))      = h0;
        *(bf8*)((char*)ats + swz64(row, khb + 16)) = h1v;
        #pragma unroll
        for (int i = 0; i < 2; ++i) {
            int c = t + i * 256; int col = c >> 3; int gg = (c & 7) ^ (col & 7);
            gload_lds16(wt + (size_t)(c0 + col) * D_ + kk0 + gg * 8, (char*)wts + c * 16);
        }
        __syncthreads();
        #pragma unroll
        for (int ks = 0; ks < 2; ++ks) {
            bf8 bv = *(const bf8*)((const char*)wts + swz64(wid * 16 + l15, ks * 64 + hi * 16));
            #pragma unroll
            for (int fr = 0; fr < 4; ++fr) {
                bf8 av = *(const bf8*)((const char*)ats + swz64(fr * 16 + l15, ks * 64 + hi * 16));
                acc[fr] = __builtin_amdgcn_mfma_f32_16x16x32_bf16(av, bv, acc[fr], 0, 0, 0);
            }
        }
        __syncthreads();
    }
    const int col = c0 + wid * 16 + l15;
    if (isA) {
        const float bb = b1[col];
        #pragma unroll
        for (int fr = 0; fr < 4; ++fr)
            #pragma unroll
            for (int j = 0; j < 4; ++j)
                aproj[(size_t)(rows0 + fr * 16 + hi * 4 + j) * H1_ + col] = acc[fr][j] + bb;
    } else {
        #pragma unroll
        for (int fr = 0; fr < 4; ++fr)
            #pragma unroll
            for (int j = 0; j < 4; ++j)
                bprojh[(size_t)(rows0 + fr * 16 + hi * 4 + j) * H1_ + col] = (__bf16)acc[fr][j];
    }
}

// ---------------- k_main: pipelined fused layer2+layer3 ---------------------
__global__ __launch_bounds__(512, 1) void k_main(
    const float* __restrict__ aproj, const __bf16* __restrict__ bprojh,
    const __bf16* __restrict__ w2T, const float* __restrict__ b2,
    const float* __restrict__ w3, const float* __restrict__ b3,
    float* __restrict__ outp) {
    __shared__ __bf16 h1s[2][256 * 32];   // 2 x 16 KB
    __shared__ __bf16 w2s[2][256 * 32];   // 2 x 16 KB
    __shared__ float  part[4][256];       // 4 KB

    const int t = threadIdx.x;
    const int l15 = t & 15, hi = (t >> 4) & 3, wid = t >> 6;
    const int wr = wid >> 2, wc = wid & 3;
    const int g = blockIdx.x;
    const int an0 = g & ~1;               // two consecutive (b*N+n) rows per block
    const int m0 = (g & 1) << 7;          // m half
    const int b_blk = an0 >> 10;

    // h1-build mapping: thread -> (pair-row r, k-half kh)
    const int r = t >> 1;                 // 0..255
    const int kh = (t & 1) << 4;          // 0 or 16 within BK=32
    const float*  ap_base = aproj  + (size_t)(an0 + (r >> 7)) * H1_ + kh;
    const __bf16* bp_base = bprojh + (size_t)(b_blk * M_ + m0 + (r & 127)) * H1_ + kh;

#define STAGE_W2(buf, kk0) do {                                                   \
    _Pragma("unroll")                                                             \
    for (int i_ = 0; i_ < 2; ++i_) {                                              \
        int c_ = t + i_ * 512; int row2_ = c_ >> 3;                               \
        int us_ = (c_ & 7) ^ (row2_ & 7);                                         \
        int col_ = row2_ * 2 + (us_ >> 2); int g_ = us_ & 3;                      \
        gload_lds16(w2T + (size_t)col_ * H1_ + (kk0) + g_ * 8,                    \
                    (char*)(&w2s[(buf)][0]) + c_ * 16);                           \
    } } while (0)

#define BUILD_H1(buf, A0, A1, A2, A3, BP0, BP1) do {                              \
    bf8 h0_, h1_;                                                                 \
    _Pragma("unroll")                                                             \
    for (int j_ = 0; j_ < 4; ++j_) {                                              \
        h0_[j_]     = (__bf16)fmaxf(A0[j_] + (float)BP0[j_],     0.0f);           \
        h0_[4 + j_] = (__bf16)fmaxf(A1[j_] + (float)BP0[4 + j_], 0.0f);           \
        h1_[j_]     = (__bf16)fmaxf(A2[j_] + (float)BP1[j_],     0.0f);           \
        h1_[4 + j_] = (__bf16)fmaxf(A3[j_] + (float)BP1[4 + j_], 0.0f);           \
    }                                                                             \
    *(bf8*)((char*)(&h1s[(buf)][0]) + swz(r, kh * 2))      = h0_;                 \
    *(bf8*)((char*)(&h1s[(buf)][0]) + swz(r, kh * 2 + 16)) = h1_;                 \
    } while (0)

    f4 acc[8][4];
    #pragma unroll
    for (int fr = 0; fr < 8; ++fr)
        #pragma unroll
        for (int cf = 0; cf < 4; ++cf) acc[fr][cf] = (f4)0.0f;

    // ---- prologue: W2(0), h1(0) resident; W2(1) in flight ----
    STAGE_W2(0, 0);
    {
        f4 a0 = *(const f4*)(ap_base), a1 = *(const f4*)(ap_base + 4),
           a2 = *(const f4*)(ap_base + 8), a3 = *(const f4*)(ap_base + 12);
        bf8 b0 = *(const bf8*)(bp_base), b1v = *(const bf8*)(bp_base + 8);
        BUILD_H1(0, a0, a1, a2, a3, b0, b1v);
    }
    STAGE_W2(1, 32);
    asm volatile("s_waitcnt lgkmcnt(0)" ::: "memory");
    __builtin_amdgcn_s_barrier();

    #pragma unroll 1
    for (int kt = 0; kt < 16; ++kt) {
        const int cur = kt & 1;
        // A: fragments + MFMA cluster
        {
            bf8 av[8], bv[4];
            #pragma unroll
            for (int fr = 0; fr < 8; ++fr) {
                int rw = wr * 128 + fr * 16 + l15;
                av[fr] = *(const bf8*)((const char*)(&h1s[cur][0]) + swz(rw, hi * 16));
            }
            #pragma unroll
            for (int cf = 0; cf < 4; ++cf) {
                int cl = wc * 64 + cf * 16 + l15;
                bv[cf] = *(const bf8*)((const char*)(&w2s[cur][0]) + swz(cl, hi * 16));
            }
            __builtin_amdgcn_s_setprio(1);
            #pragma unroll
            for (int fr = 0; fr < 8; ++fr)
                #pragma unroll
                for (int cf = 0; cf < 4; ++cf)
                    acc[fr][cf] = __builtin_amdgcn_mfma_f32_16x16x32_bf16(av[fr], bv[cf], acc[fr][cf], 0, 0, 0);
            __builtin_amdgcn_s_setprio(0);
        }
        if (kt == 15) break;
        // B: issue next h1 operand loads (stay in flight across the wait)
        const int kk1 = (kt + 1) * 32;
        f4 a0 = *(const f4*)(ap_base + kk1), a1 = *(const f4*)(ap_base + kk1 + 4),
           a2 = *(const f4*)(ap_base + kk1 + 8), a3 = *(const f4*)(ap_base + kk1 + 12);
        bf8 b0 = *(const bf8*)(bp_base + kk1), b1v = *(const bf8*)(bp_base + kk1 + 8);
        // retire exactly the 2 W2(kt+1) global_load_lds chunks; keep 6 reg loads flying
        asm volatile("s_waitcnt vmcnt(6) lgkmcnt(0)" ::: "memory");
        __builtin_amdgcn_s_barrier();
        // C: stage W2(kt+2) into the buffer we just finished reading (flies ~1 full iter)
        if (kt < 14) STAGE_W2(cur, (kt + 2) * 32);
        // D: build h1(kt+1)
        BUILD_H1(cur ^ 1, a0, a1, a2, a3, b0, b1v);
        // E: make h1 writes visible; do NOT drain vmcnt (W2(kt+2) stays in flight)
        asm volatile("s_waitcnt lgkmcnt(0)" ::: "memory");
        __builtin_amdgcn_s_barrier();
    }

    // ---- epilogue: relu(+b2) dot W3, reduce over H2 ----
    float b2v[4], w3v[4];
    #pragma unroll
    for (int cf = 0; cf < 4; ++cf) {
        int col = wc * 64 + cf * 16 + l15;
        b2v[cf] = b2[col]; w3v[cf] = w3[col];
    }
    #pragma unroll
    for (int fr = 0; fr < 8; ++fr) {
        #pragma unroll
        for (int j = 0; j < 4; ++j) {
            float s = 0.0f;
            #pragma unroll
            for (int cf = 0; cf < 4; ++cf)
                s += fmaxf(acc[fr][cf][j] + b2v[cf], 0.0f) * w3v[cf];
            s += __shfl_xor(s, 1); s += __shfl_xor(s, 2);
            s += __shfl_xor(s, 4); s += __shfl_xor(s, 8);
            if (l15 == 0) part[wc][wr * 128 + fr * 16 + hi * 4 + j] = s;
        }
    }
    __syncthreads();
    if (t < 256) {
        float o = part[0][t] + part[1][t] + part[2][t] + part[3][t] + b3[0];
        outp[(size_t)(an0 + (t >> 7)) * M_ + m0 + (t & 127)] = o;
    }
#undef STAGE_W2
#undef BUILD_H1
}

extern "C" void kernel_launch(void* const* d_in, const int* in_sizes, int n_in,
                              void* d_out, int out_size, void* d_ws, size_t ws_size,
                              hipStream_t stream) {
    (void)in_sizes; (void)n_in; (void)out_size; (void)ws_size;
    const float* PhiA = (const float*)d_in[0];
    const float* PhiB = (const float*)d_in[1];
    const float* W1a  = (const float*)d_in[2];
    const float* W1b  = (const float*)d_in[3];
    const float* b1   = (const float*)d_in[4];
    const float* W2   = (const float*)d_in[5];
    const float* b2   = (const float*)d_in[6];
    const float* W3   = (const float*)d_in[7];
    const float* b3   = (const float*)d_in[8];
    float* out = (float*)d_out;

    char* ws = (char*)d_ws;
    float*  aproj  = (float*)(ws);                  // 2048*512*4 = 4,194,304
    __bf16* bprojh = (__bf16*)(ws + 4194304);       //  512*512*2 =   524,288
    __bf16* w1aT   = (__bf16*)(ws + 4718592);       //   589,824
    __bf16* w1bT   = (__bf16*)(ws + 5308416);       //   589,824
    __bf16* w2T    = (__bf16*)(ws + 5898240);       //   262,144  (total ~6.2 MB)

    k_tr  <<<704, 256, 0, stream>>>(W1a, W1b, W2, w1aT, w1bT, w2T);
    k_proj<<<dim3(40, 8), 256, 0, stream>>>(PhiA, PhiB, w1aT, w1bT, b1, aproj, bprojh);
    k_main<<<2048, 512, 0, stream>>>(aproj, bprojh, w2T, b2, W3, b3, out);
}

// Round 4
// 236.712 us; speedup vs baseline: 1.4470x; 1.3163x over previous
//
#include <hip/hip_runtime.h>

typedef float  f4  __attribute__((ext_vector_type(4)));
typedef __bf16 bf8 __attribute__((ext_vector_type(8)));

constexpr int B_ = 2, N_ = 1024, M_ = 256, D_ = 576, H1_ = 512, H2_ = 256;

__device__ __forceinline__ void gload_lds16(const void* g, void* l) {
    __builtin_amdgcn_global_load_lds((const __attribute__((address_space(1))) void*)g,
                                     (__attribute__((address_space(3))) void*)l, 16, 0, 0);
}

// ---------------- k_prep: weight transposes + Phi f32->bf16 ----------------
__global__ __launch_bounds__(256) void k_prep(
    const float* __restrict__ PhiA, const float* __restrict__ PhiB,
    const float* __restrict__ W1a, const float* __restrict__ W1b, const float* __restrict__ W2,
    __bf16* __restrict__ phiAb, __bf16* __restrict__ phiBb,
    __bf16* __restrict__ w1aT, __bf16* __restrict__ w1bT, __bf16* __restrict__ w2T) {
    __shared__ float tl[32][33];
    int bid = blockIdx.x;
    if (bid < 704) {
        const float* src; __bf16* dst; int R, C, t0;
        if (bid < 288)      { src = W1a; dst = w1aT; R = D_;  C = H1_; t0 = bid; }
        else if (bid < 576) { src = W1b; dst = w1bT; R = D_;  C = H1_; t0 = bid - 288; }
        else                { src = W2;  dst = w2T;  R = H1_; C = H2_; t0 = bid - 576; }
        const int tilesC = C / 32;
        const int r0 = (t0 / tilesC) * 32, c0 = (t0 % tilesC) * 32;
        const int tx = threadIdx.x & 31, ty = threadIdx.x >> 5;
        #pragma unroll
        for (int i = 0; i < 4; ++i)
            tl[ty + i * 8][tx] = src[(size_t)(r0 + ty + i * 8) * C + c0 + tx];
        __syncthreads();
        #pragma unroll
        for (int i = 0; i < 4; ++i)
            dst[(size_t)(c0 + ty + i * 8) * R + r0 + tx] = (__bf16)tl[tx][ty + i * 8];
    } else {
        int i = (bid - 704) * 2048 + threadIdx.x * 8;
        const float* s; __bf16* d;
        if (bid < 1280) { s = PhiA; d = phiAb; }          // 576 blocks, 1179648 elems
        else            { s = PhiB; d = phiBb; i -= 1179648; }  // 144 blocks
        f4 v0 = *(const f4*)(s + i), v1 = *(const f4*)(s + i + 4);
        bf8 o;
        #pragma unroll
        for (int j = 0; j < 4; ++j) { o[j] = (__bf16)v0[j]; o[4 + j] = (__bf16)v1[j]; }
        *(bf8*)(d + i) = o;
    }
}

// ------- k_proj: phib(bf16) @ W1T -> aproj(f32,+b1) / bproj(bf16) ----------
// 64r x 64c tile, 4 waves (2x2), BK=64, double-buffered, 1 barrier/iter.
__global__ __launch_bounds__(256, 2) void k_proj(
    const __bf16* __restrict__ phiAb, const __bf16* __restrict__ phiBb,
    const __bf16* __restrict__ w1aT, const __bf16* __restrict__ w1bT,
    const float* __restrict__ b1, float* __restrict__ aproj, __bf16* __restrict__ bprojh) {
    __shared__ __bf16 as_[2][64 * 64];   // 8KB each, row=128B, XOR swz
    __shared__ __bf16 ws_[2][64 * 64];
    const int t = threadIdx.x, l15 = t & 15, g = (t >> 4) & 3, wid = t >> 6;
    const int wr = wid >> 1, wc = wid & 1;
    const int bx = blockIdx.x, c0 = blockIdx.y * 64;
    const __bf16* src; const __bf16* wt; int rows0; bool isA;
    if (bx < 32) { src = phiAb; wt = w1aT; rows0 = bx * 64;        isA = true; }
    else         { src = phiBb; wt = w1bT; rows0 = (bx - 32) * 64; isA = false; }

#define STG_P(arr, gbase, grow0, kk) do {                                         \
    _Pragma("unroll")                                                             \
    for (int i_ = 0; i_ < 2; ++i_) {                                              \
        int c_ = t + i_ * 256; int row_ = c_ >> 3; int gg_ = (c_ & 7) ^ (row_ & 7);\
        gload_lds16((gbase) + (size_t)((grow0) + row_) * D_ + (kk) + gg_ * 8,     \
                    (char*)(arr) + c_ * 16);                                      \
    } } while (0)

    f4 acc[2][2];
    #pragma unroll
    for (int fr = 0; fr < 2; ++fr)
        #pragma unroll
        for (int cf = 0; cf < 2; ++cf) acc[fr][cf] = (f4)0.0f;

    STG_P(as_[0], src, rows0, 0); STG_P(ws_[0], wt, c0, 0);
    asm volatile("s_waitcnt vmcnt(0)" ::: "memory");
    __builtin_amdgcn_s_barrier();
    STG_P(as_[1], src, rows0, 64); STG_P(ws_[1], wt, c0, 64);

    #pragma unroll 1
    for (int kt = 0; kt < 9; ++kt) {                  // K = 576 = 9*64
        const int cur = kt & 1;
        #pragma unroll
        for (int ks = 0; ks < 2; ++ks) {
            bf8 av[2], bv[2];
            #pragma unroll
            for (int fr = 0; fr < 2; ++fr) {
                int row = wr * 32 + fr * 16 + l15;
                av[fr] = *(const bf8*)((const char*)(&as_[cur][0]) +
                         row * 128 + ((ks * 64 + g * 16) ^ ((row & 7) << 4)));
            }
            #pragma unroll
            for (int cf = 0; cf < 2; ++cf) {
                int col = wc * 32 + cf * 16 + l15;
                bv[cf] = *(const bf8*)((const char*)(&ws_[cur][0]) +
                         col * 128 + ((ks * 64 + g * 16) ^ ((col & 7) << 4)));
            }
            #pragma unroll
            for (int fr = 0; fr < 2; ++fr)
                #pragma unroll
                for (int cf = 0; cf < 2; ++cf)
                    acc[fr][cf] = __builtin_amdgcn_mfma_f32_16x16x32_bf16(av[fr], bv[cf], acc[fr][cf], 0, 0, 0);
        }
        if (kt == 8) break;
        asm volatile("s_waitcnt vmcnt(0) lgkmcnt(0)" ::: "memory");
        __builtin_amdgcn_s_barrier();
        if (kt < 7) { STG_P(as_[cur], src, rows0, (kt + 2) * 64); STG_P(ws_[cur], wt, c0, (kt + 2) * 64); }
    }

    #pragma unroll
    for (int fr = 0; fr < 2; ++fr)
        #pragma unroll
        for (int cf = 0; cf < 2; ++cf) {
            int col = c0 + wc * 32 + cf * 16 + l15;
            int row = rows0 + wr * 32 + fr * 16 + g * 4;
            if (isA) {
                float bb = b1[col];
                #pragma unroll
                for (int j = 0; j < 4; ++j)
                    aproj[(size_t)(row + j) * H1_ + col] = acc[fr][cf][j] + bb;
            } else {
                #pragma unroll
                for (int j = 0; j < 4; ++j)
                    bprojh[(size_t)(row + j) * H1_ + col] = (__bf16)acc[fr][cf][j];
            }
        }
#undef STG_P
}

// ---------------- k_main: register-built h1, block = 16n x 16m x 256 H2 ----
__global__ __launch_bounds__(512, 2) void k_main(
    const float* __restrict__ aproj, const __bf16* __restrict__ bprojh,
    const __bf16* __restrict__ w2T, const float* __restrict__ b2,
    const float* __restrict__ w3, const float* __restrict__ b3,
    float* __restrict__ outp) {
    __shared__ float  apl[16 * 512];      // 32KB, row 2048B, linear (broadcast reads)
    __shared__ __bf16 bpl[16 * 512];      // 16KB, row 1024B, XOR swz
    __shared__ __bf16 w2l[2][256 * 64];   // 2x32KB, row 128B, XOR swz
    __shared__ float  part[2][256];       // 2KB   -> 114KB total

    const int t = threadIdx.x, l15 = t & 15, g = (t >> 4) & 3, wid = t >> 6;
    const int wr = wid >> 1, wc = wid & 1;      // 4 x 2 wave grid
    const int bid = blockIdx.x;
    const int bn0 = (bid >> 4) << 4;            // 16 aproj rows (b*N+n)
    const int m0 = (bid & 15) << 4;
    const int bprow0 = ((bn0 >> 10) << 8) + m0; // batch*256 + m0

#define STAGE_W2M(buf, kk) do {                                                   \
    _Pragma("unroll")                                                             \
    for (int i_ = 0; i_ < 4; ++i_) {                                              \
        int c_ = t + i_ * 512; int col_ = c_ >> 3; int gg_ = (c_ & 7) ^ (col_ & 7);\
        gload_lds16(w2T + (size_t)col_ * H1_ + (kk) + gg_ * 8,                    \
                    (char*)(&w2l[(buf)][0]) + c_ * 16);                           \
    } } while (0)

    // ap: 16 rows x 512 f32, linear dest (c*16 bytes)
#define STAGE_AP() do {                                                           \
    _Pragma("unroll")                                                             \
    for (int i_ = 0; i_ < 4; ++i_) {                                              \
        int c_ = t + i_ * 512;                                                    \
        gload_lds16(aproj + (size_t)(bn0 + (c_ >> 7)) * H1_ + (c_ & 127) * 4,     \
                    (char*)apl + c_ * 16);                                        \
    } } while (0)

    // bp: 16 rows x 512 bf16, swizzled source so LDS holds row-XOR layout
#define STAGE_BP() do {                                                           \
    _Pragma("unroll")                                                             \
    for (int i_ = 0; i_ < 2; ++i_) {                                              \
        int c_ = t + i_ * 512; int row_ = c_ >> 6;                                \
        int wb_ = (((c_ & 63) * 16) ^ ((row_ & 7) << 4)) >> 1;                    \
        gload_lds16(bprojh + (size_t)(bprow0 + row_) * H1_ + wb_,                 \
                    (char*)bpl + c_ * 16);                                        \
    } } while (0)

    f4 acc[4][8];
    #pragma unroll
    for (int fr = 0; fr < 4; ++fr)
        #pragma unroll
        for (int cf = 0; cf < 8; ++cf) acc[fr][cf] = (f4)0.0f;

    float b2v[8], w3v[8];
    #pragma unroll
    for (int cf = 0; cf < 8; ++cf) {
        int col = wc * 128 + cf * 16 + l15;
        b2v[cf] = b2[col]; w3v[cf] = w3[col];
    }

    STAGE_AP(); STAGE_BP(); STAGE_W2M(0, 0);
    asm volatile("s_waitcnt vmcnt(0)" ::: "memory");
    __builtin_amdgcn_s_barrier();
    STAGE_W2M(1, 64);

    #pragma unroll 1
    for (int kt = 0; kt < 8; ++kt) {              // K = 512 = 8*64
        const int cur = kt & 1;
        const int kb = kt * 64;
        #pragma unroll
        for (int ks = 0; ks < 2; ++ks) {
            // bp chunk: lane m=l15, k = kb+ks*32+g*8 .. +8  (reused across fr and cf)
            bf8 bpv = *(const bf8*)((const char*)bpl + l15 * 1024 +
                      (((kb + ks * 32 + g * 8) * 2) ^ ((l15 & 7) << 4)));
            float bpf[8];
            #pragma unroll
            for (int j = 0; j < 8; ++j) bpf[j] = (float)bpv[j];
            // W2 fragments for this k-slice
            bf8 bv[8];
            #pragma unroll
            for (int cf = 0; cf < 8; ++cf) {
                int col = wc * 128 + cf * 16 + l15;
                bv[cf] = *(const bf8*)((const char*)(&w2l[cur][0]) +
                         col * 128 + ((ks * 64 + g * 16) ^ ((col & 7) << 4)));
            }
            __builtin_amdgcn_s_setprio(1);
            #pragma unroll
            for (int fr = 0; fr < 4; ++fr) {
                const int n_l = wr * 4 + fr;
                const float* apw = apl + n_l * 512 + kb + ks * 32 + g * 8;
                f4 a0 = *(const f4*)apw, a1 = *(const f4*)(apw + 4);
                bf8 av;
                #pragma unroll
                for (int j = 0; j < 4; ++j) {
                    av[j]     = (__bf16)fmaxf(a0[j] + bpf[j],     0.0f);
                    av[4 + j] = (__bf16)fmaxf(a1[j] + bpf[4 + j], 0.0f);
                }
                #pragma unroll
                for (int cf = 0; cf < 8; ++cf)
                    acc[fr][cf] = __builtin_amdgcn_mfma_f32_16x16x32_bf16(av, bv[cf], acc[fr][cf], 0, 0, 0);
            }
            __builtin_amdgcn_s_setprio(0);
        }
        if (kt == 7) break;
        asm volatile("s_waitcnt vmcnt(0) lgkmcnt(0)" ::: "memory");
        __builtin_amdgcn_s_barrier();
        if (kt < 6) STAGE_W2M(cur, (kt + 2) * 64);
    }

    // epilogue: relu(acc+b2) dot w3, reduce 16 lanes + 2 wc groups
    #pragma unroll
    for (int fr = 0; fr < 4; ++fr) {
        #pragma unroll
        for (int j = 0; j < 4; ++j) {
            float s = 0.0f;
            #pragma unroll
            for (int cf = 0; cf < 8; ++cf)
                s += fmaxf(acc[fr][cf][j] + b2v[cf], 0.0f) * w3v[cf];
            s += __shfl_xor(s, 1); s += __shfl_xor(s, 2);
            s += __shfl_xor(s, 4); s += __shfl_xor(s, 8);
            if (l15 == 0) part[wc][wr * 64 + fr * 16 + g * 4 + j] = s;
        }
    }
    __syncthreads();
    if (t < 256) {
        float o = part[0][t] + part[1][t] + b3[0];
        outp[(size_t)(bn0 + (t >> 4)) * M_ + m0 + (t & 15)] = o;
    }
#undef STAGE_W2M
#undef STAGE_AP
#undef STAGE_BP
}

extern "C" void kernel_launch(void* const* d_in, const int* in_sizes, int n_in,
                              void* d_out, int out_size, void* d_ws, size_t ws_size,
                              hipStream_t stream) {
    (void)in_sizes; (void)n_in; (void)out_size; (void)ws_size;
    const float* PhiA = (const float*)d_in[0];
    const float* PhiB = (const float*)d_in[1];
    const float* W1a  = (const float*)d_in[2];
    const float* W1b  = (const float*)d_in[3];
    const float* b1   = (const float*)d_in[4];
    const float* W2   = (const float*)d_in[5];
    const float* b2   = (const float*)d_in[6];
    const float* W3   = (const float*)d_in[7];
    const float* b3   = (const float*)d_in[8];
    float* out = (float*)d_out;

    char* ws = (char*)d_ws;
    float*  aproj  = (float*)(ws);                  // 4,194,304
    __bf16* bprojh = (__bf16*)(ws + 4194304);       //   524,288
    __bf16* phiAb  = (__bf16*)(ws + 4718592);       // 2,359,296
    __bf16* phiBb  = (__bf16*)(ws + 7077888);       //   589,824
    __bf16* w1aT   = (__bf16*)(ws + 7667712);       //   589,824
    __bf16* w1bT   = (__bf16*)(ws + 8257536);       //   589,824
    __bf16* w2T    = (__bf16*)(ws + 8847360);       //   262,144  (total ~9.1 MB)

    k_prep<<<1424, 256, 0, stream>>>(PhiA, PhiB, W1a, W1b, W2, phiAb, phiBb, w1aT, w1bT, w2T);
    k_proj<<<dim3(40, 8), 256, 0, stream>>>(phiAb, phiBb, w1aT, w1bT, b1, aproj, bprojh);
    k_main<<<2048, 512, 0, stream>>>(aproj, bprojh, w2T, b2, W3, b3, out);
}